// Round 5
// baseline (472.750 us; speedup 1.0000x reference)
//
#include <hip/hip_runtime.h>

#define ALPHA 0.9f
#define BETA  0.8f
#define XS 36960   // padded row stride for x and w1p (multiple of 4, >= 36954)

// ---------------------------------------------------------------------------
// state: 128x3x224x224  conv1 32x3x8x8 s4 -> f1 128x32x55x55
// f1 -> conv2 64x32x4x4 s2 -> f2 128x64x26x26
// f2 -> conv3 64x64x3x3 s1 -> x rows (36864 + 90 history, pad to 36960)
// h1 = x @ w1.T + b1 (128x128), T=10 LIF recurrence -> out 128x9
// ---------------------------------------------------------------------------

__global__ __launch_bounds__(256) void transpose_weights_kernel(
    const float* __restrict__ cw1, const float* __restrict__ cw2,
    const float* __restrict__ cw3, const float* __restrict__ w2,
    float* __restrict__ wt1, float* __restrict__ wt2,
    float* __restrict__ wt3, float* __restrict__ w2t) {
  int i = blockIdx.x * 256 + threadIdx.x;   // grid covers 36864
  if (i < 6144)  { int k = i >> 5, oc = i & 31;  wt1[k * 32 + oc] = cw1[oc * 192 + k]; }
  if (i < 32768) { int k = i >> 6, oc = i & 63;  wt2[k * 64 + oc] = cw2[oc * 512 + k]; }
  if (i < 36864) { int k = i / 64, oc = i % 64;  wt3[k * 64 + oc] = cw3[oc * 576 + k]; }
  if (i < 32768) { int j = i >> 7, k = i & 127;  w2t[k * 256 + j] = w2[i]; }
}

// Copy w1 (128 x 36954) into padded rows (128 x 36960), zero tail.
__global__ __launch_bounds__(256) void pad_w1_kernel(
    const float* __restrict__ w1, float* __restrict__ w1p) {
  int i = blockIdx.x * 256 + threadIdx.x;   // float2 slots: 128 * 18480
  if (i < 128 * 18480) {
    int j = i / 18480, c = i - j * 18480;
    float2 v;
    if (c < 18477) v = *(const float2*)&w1[(size_t)j * 36954 + c * 2];
    else v = make_float2(0.f, 0.f);
    *(float2*)&w1p[(size_t)j * XS + c * 2] = v;
  }
}

// conv1: 256-thr blocks = 4 oh-waves; lanes = ow; float4 px loads (16B-aligned
// since lane base is ow*4 floats). 32 accs, 2 dwordx4 + 256 FMA per (c,kh).
__global__ __launch_bounds__(256) void conv1_kernel(
    const float* __restrict__ in, const float* __restrict__ wt, // [192][32]
    const float* __restrict__ bias, float* __restrict__ out) {
  int wv = threadIdx.x >> 6;            // wave in block: 0..3
  int ow = threadIdx.x & 63;            // active < 55
  int oh = blockIdx.x * 4 + wv;         // 0..55 (55 skipped)
  int n  = blockIdx.y;
  if (oh >= 55 || ow >= 55) return;
  float acc[32];
#pragma unroll
  for (int o = 0; o < 32; ++o) acc[o] = 0.f;
  const float* ib = in + (size_t)n * 3 * 224 * 224 + (oh * 4) * 224 + ow * 4;
#pragma unroll 1
  for (int c = 0; c < 3; ++c) {
#pragma unroll
    for (int kh = 0; kh < 8; ++kh) {
      const float* row = ib + c * 224 * 224 + kh * 224;
      float4 p0 = *(const float4*)row;
      float4 p1 = *(const float4*)(row + 4);
      float px[8] = {p0.x, p0.y, p0.z, p0.w, p1.x, p1.y, p1.z, p1.w};
      int kb = (c * 8 + kh) * 8;
#pragma unroll
      for (int kw = 0; kw < 8; ++kw)
#pragma unroll
        for (int o = 0; o < 32; ++o)
          acc[o] = fmaf(px[kw], wt[(kb + kw) * 32 + o], acc[o]);
    }
  }
  float* ob = out + ((size_t)(n * 32) * 55 + oh) * 55 + ow;
#pragma unroll
  for (int o = 0; o < 32; ++o) {
    float v = acc[o] + bias[o];
    ob[(size_t)o * 55 * 55] = v > 0.f ? v : 0.f;
  }
}

// conv2: 256-thr blocks (4 waves), grid (3, n=128, ocq=4), 16 accs/thread
__global__ __launch_bounds__(256) void conv2_kernel(
    const float* __restrict__ in,  // f1 128x32x55x55
    const float* __restrict__ wt,  // [512][64]
    const float* __restrict__ bias, float* __restrict__ out) {
  int n = blockIdx.y;
  int ob0 = blockIdx.z * 16;                  // 0,16,32,48
  int pos = blockIdx.x * 256 + threadIdx.x;   // active < 676
  if (pos >= 676) return;
  float acc[16];
#pragma unroll
  for (int o = 0; o < 16; ++o) acc[o] = 0.f;
  int oh = pos / 26, ow = pos % 26;
  const float* ib = in + (size_t)n * 32 * 55 * 55 + (oh * 2) * 55 + ow * 2;
  const float* wb = wt + ob0;
#pragma unroll 2
  for (int c = 0; c < 32; ++c) {
#pragma unroll
    for (int kh = 0; kh < 4; ++kh) {
      const float* row = ib + c * 55 * 55 + kh * 55;
#pragma unroll
      for (int kw = 0; kw < 4; ++kw) {
        float px = row[kw];
        int k = (c * 4 + kh) * 4 + kw;
#pragma unroll
        for (int o = 0; o < 16; ++o)
          acc[o] = fmaf(px, wb[k * 64 + o], acc[o]);
      }
    }
  }
  float* obp = out + ((size_t)(n * 64 + ob0) * 26 + oh) * 26 + ow;
#pragma unroll
  for (int o = 0; o < 16; ++o) {
    float v = acc[o] + bias[ob0 + o];
    obp[(size_t)o * 26 * 26] = v > 0.f ? v : 0.f;
  }
}

// conv3: 192-thr blocks (3 waves), grid (3, n=128, ocq=4), 16 accs/thread
__global__ __launch_bounds__(192) void conv3_kernel(
    const float* __restrict__ in,  // f2 128x64x26x26
    const float* __restrict__ wt,  // [576][64]
    const float* __restrict__ bias, float* __restrict__ x) {
  int n = blockIdx.y;
  int ob0 = blockIdx.z * 16;                 // 0,16,32,48
  int pos = blockIdx.x * 192 + threadIdx.x;  // < 576 always
  int oh = pos / 24, ow = pos % 24;
  float acc[16];
#pragma unroll
  for (int o = 0; o < 16; ++o) acc[o] = 0.f;
  const float* wb = wt + ob0;
#pragma unroll 2
  for (int c = 0; c < 64; ++c) {
#pragma unroll
    for (int kh = 0; kh < 3; ++kh) {
      const float* row = in + ((size_t)(n * 64 + c) * 26 + oh + kh) * 26 + ow;
#pragma unroll
      for (int kw = 0; kw < 3; ++kw) {
        float px = row[kw];
        int k = (c * 3 + kh) * 3 + kw;
#pragma unroll
        for (int o = 0; o < 16; ++o)
          acc[o] = fmaf(px, wb[k * 64 + o], acc[o]);
      }
    }
  }
  float* xb = x + (size_t)n * XS + pos;
#pragma unroll
  for (int o = 0; o < 16; ++o) {
    float v = acc[o] + bias[ob0 + o];
    xb[(size_t)(ob0 + o) * 576] = v > 0.f ? v : 0.f;
  }
}

// history -> x[:, 36864:36954], zero the pad to 36960
__global__ __launch_bounds__(256) void histpack_kernel(
    const float* __restrict__ h, float* __restrict__ x) {
  int i = blockIdx.x * 256 + threadIdx.x;
  if (i < 128 * 96) {
    int n = i / 96, k = i % 96;
    x[(size_t)n * XS + 36864 + k] = (k < 90) ? h[n * 90 + k] : 0.f;
  }
}

// FC1: register-blocked split-K GEMM. Block kt covers k in [kt*128, kt*128+128)
// as 4 staged chunks of KC=32. Full 128b x 128j tile per block; thread owns
// an 8b x 8j interleaved sub-tile -> 64 accs, 256 FMA per 16 ds_read_b128.
#define FC1_KT 289
__global__ __launch_bounds__(256) void fc1_kernel(
    const float* __restrict__ x, const float* __restrict__ w1p,
    float* __restrict__ P) {
  int kt = blockIdx.x;        // 0..288
  int t  = threadIdx.x;
  int bq = t & 15, jq = t >> 4;
  __shared__ float xs[128 * 36];
  __shared__ float wsm[128 * 36];
  float acc[8][8];
#pragma unroll
  for (int bb = 0; bb < 8; ++bb)
#pragma unroll
    for (int jj = 0; jj < 8; ++jj) acc[bb][jj] = 0.f;

  int cs = t & 7;          // float4 column for staging (0..7)
  int rs = t >> 3;         // row base for staging (0..31), 4 passes
#pragma unroll 1
  for (int s = 0; s < 4; ++s) {
    int k0 = kt * 128 + s * 32;
    __syncthreads();
#pragma unroll
    for (int p = 0; p < 4; ++p) {
      int r = rs + p * 32;
      int gk = k0 + cs * 4;
      float4 xv, wv;
      if (gk < 36954) {
        xv = *(const float4*)&x[(size_t)r * XS + gk];
        wv = *(const float4*)&w1p[(size_t)r * XS + gk];
      } else {
        xv = make_float4(0.f, 0.f, 0.f, 0.f);
        wv = make_float4(0.f, 0.f, 0.f, 0.f);
      }
      *(float4*)&xs[r * 36 + cs * 4] = xv;
      *(float4*)&wsm[r * 36 + cs * 4] = wv;
    }
    __syncthreads();
#pragma unroll 1
    for (int kk = 0; kk < 32; kk += 4) {
      float4 xv[8], wv[8];
#pragma unroll
      for (int i = 0; i < 8; ++i)
        xv[i] = *(const float4*)&xs[(bq + 16 * i) * 36 + kk];
#pragma unroll
      for (int i = 0; i < 8; ++i)
        wv[i] = *(const float4*)&wsm[(jq + 16 * i) * 36 + kk];
#pragma unroll
      for (int bb = 0; bb < 8; ++bb)
#pragma unroll
        for (int jj = 0; jj < 8; ++jj) {
          acc[bb][jj] = fmaf(xv[bb].x, wv[jj].x, acc[bb][jj]);
          acc[bb][jj] = fmaf(xv[bb].y, wv[jj].y, acc[bb][jj]);
          acc[bb][jj] = fmaf(xv[bb].z, wv[jj].z, acc[bb][jj]);
          acc[bb][jj] = fmaf(xv[bb].w, wv[jj].w, acc[bb][jj]);
        }
    }
  }
  float* Pb = P + (size_t)kt * 16384;
#pragma unroll
  for (int bb = 0; bb < 8; ++bb)
#pragma unroll
    for (int jj = 0; jj < 8; ++jj)
      Pb[(bq + 16 * bb) * 128 + jq + 16 * jj] = acc[bb][jj];
}

// Reduce P over kt: h1s[b][j] = sum_kt P[kt][b][j] + b1[j]. All lanes active,
// coalesced 128-lane rows, 4 partial accumulators.
__global__ __launch_bounds__(256) void reduce_p_kernel(
    const float* __restrict__ P, const float* __restrict__ b1,
    float* __restrict__ h1s) {
  int idx = blockIdx.x * 256 + threadIdx.x;   // 0..16383
  int j = idx & 127;
  float a0 = 0.f, a1 = 0.f, a2 = 0.f, a3 = 0.f;
  int kt = 0;
#pragma unroll 2
  for (; kt + 3 < FC1_KT; kt += 4) {
    a0 += P[(size_t)(kt + 0) * 16384 + idx];
    a1 += P[(size_t)(kt + 1) * 16384 + idx];
    a2 += P[(size_t)(kt + 2) * 16384 + idx];
    a3 += P[(size_t)(kt + 3) * 16384 + idx];
  }
  for (; kt < FC1_KT; ++kt) a0 += P[(size_t)kt * 16384 + idx];
  h1s[idx] = ((a0 + a1) + (a2 + a3)) + b1[j];
}

// Recurrence: one block per batch row; h1 precomputed; runs T=10.
__global__ __launch_bounds__(256) void recur_kernel(
    const float* __restrict__ h1s,  // [128][128]
    const float* __restrict__ w2t,  // [128][256]
    const float* __restrict__ b2,
    const float* __restrict__ w3,   // [9][256]
    const float* __restrict__ b3,
    float* __restrict__ out) {      // [128][9]
  int b = blockIdx.x;
  int t = threadIdx.x;
  __shared__ float spk1s[128];
  __shared__ float spk2s[256];
  float h1 = 0.f, mem1 = 0.f, syn1 = 0.f;
  if (t < 128) h1 = h1s[b * 128 + t];
  float mem2 = 0.f, syn2 = 0.f;
  float b2v = b2[t];
  float mem3 = 0.f, syn3 = 0.f, pot = 0.f;
  float b3v = (t < 9) ? b3[t] : 0.f;

  for (int step = 0; step < 10; ++step) {
    if (t < 128) {
      syn1 = ALPHA * syn1 + h1;
      mem1 = BETA * mem1 + syn1;
      float s = (mem1 > 1.0f) ? 1.0f : 0.0f;
      mem1 -= s;
      spk1s[t] = s;
    }
    __syncthreads();
    float h2 = b2v;
#pragma unroll 8
    for (int k = 0; k < 128; ++k)
      h2 = fmaf(spk1s[k], w2t[k * 256 + t], h2);
    syn2 = ALPHA * syn2 + h2;
    mem2 = BETA * mem2 + syn2;
    float s2 = (mem2 > 1.0f) ? 1.0f : 0.0f;
    mem2 -= s2;
    spk2s[t] = s2;
    __syncthreads();
    if (t < 9) {
      float a0 = 0.f, a1 = 0.f, a2 = 0.f, a3 = 0.f;
      const float* wr = w3 + t * 256;
      for (int k = 0; k < 256; k += 4) {
        a0 = fmaf(spk2s[k],     wr[k],     a0);
        a1 = fmaf(spk2s[k + 1], wr[k + 1], a1);
        a2 = fmaf(spk2s[k + 2], wr[k + 2], a2);
        a3 = fmaf(spk2s[k + 3], wr[k + 3], a3);
      }
      float h3 = b3v + (a0 + a1) + (a2 + a3);
      syn3 = ALPHA * syn3 + h3;
      mem3 = BETA * mem3 + syn3;
      pot += mem3;
    }
    __syncthreads();
  }
  if (t < 9) out[b * 9 + t] = pot * 0.1f;
}

extern "C" void kernel_launch(void* const* d_in, const int* in_sizes, int n_in,
                              void* d_out, int out_size, void* d_ws, size_t ws_size,
                              hipStream_t stream) {
  const float* state   = (const float*)d_in[0];
  const float* history = (const float*)d_in[1];
  const float* cw1 = (const float*)d_in[2];
  const float* cb1 = (const float*)d_in[3];
  const float* cw2 = (const float*)d_in[4];
  const float* cb2 = (const float*)d_in[5];
  const float* cw3 = (const float*)d_in[6];
  const float* cb3 = (const float*)d_in[7];
  const float* w1  = (const float*)d_in[8];
  const float* b1  = (const float*)d_in[9];
  const float* w2  = (const float*)d_in[10];
  const float* b2  = (const float*)d_in[11];
  const float* w3  = (const float*)d_in[12];
  const float* b3  = (const float*)d_in[13];
  float* out = (float*)d_out;
  char* ws = (char*)d_ws;

  // workspace layout (bytes):
  //  [0, 49561600)   f1 (live conv1->conv2). After conv2:
  //                    xb  = [0, 18923520)          (128 x 36960)
  //                    w1p = [18923520, 37847040)   (128 x 36960)
  //  [49561600, 71712768)  f2 (live conv2->conv3). After conv3:
  //                    P   = [49561600, 68501504)   (289 x 128 x 128)
  //                    h1s = [68501504, 68567040)
  //  [71712768, ...)       small transposed weights
  float* f1  = (float*)(ws + 0);
  float* xb  = (float*)(ws + 0);
  float* w1p = (float*)(ws + 18923520);
  float* f2  = (float*)(ws + 49561600);
  float* P   = (float*)(ws + 49561600);
  float* h1s = (float*)(ws + 68501504);
  float* wt1 = (float*)(ws + 71712768);   // 24,576
  float* wt2 = (float*)(ws + 71737344);   // 131,072
  float* wt3 = (float*)(ws + 71868416);   // 147,456
  float* w2t = (float*)(ws + 72015872);   // 131,072  (end 72,146,944)

  transpose_weights_kernel<<<144, 256, 0, stream>>>(cw1, cw2, cw3, w2,
                                                    wt1, wt2, wt3, w2t);
  conv1_kernel<<<dim3(14, 128), 256, 0, stream>>>(state, wt1, cb1, f1);
  conv2_kernel<<<dim3(3, 128, 4), 256, 0, stream>>>(f1, wt2, cb2, f2);
  pad_w1_kernel<<<9240, 256, 0, stream>>>(w1, w1p);
  conv3_kernel<<<dim3(3, 128, 4), 192, 0, stream>>>(f2, wt3, cb3, xb);
  histpack_kernel<<<48, 256, 0, stream>>>(history, xb);
  fc1_kernel<<<FC1_KT, 256, 0, stream>>>(xb, w1p, P);
  reduce_p_kernel<<<64, 256, 0, stream>>>(P, b1, h1s);
  recur_kernel<<<128, 256, 0, stream>>>(h1s, w2t, b2, w3, b3, out);
}

// Round 7
// 447.855 us; speedup vs baseline: 1.0556x; 1.0556x over previous
//
#include <hip/hip_runtime.h>

#define ALPHA 0.9f
#define BETA  0.8f
#define XS 36960   // padded row stride for x and w1p

typedef _Float16 f16;
typedef _Float16 f16x8 __attribute__((ext_vector_type(8)));
typedef float f32x4 __attribute__((ext_vector_type(4)));

// ---------------------------------------------------------------------------
// state: 128x3x224x224  conv1 32x3x8x8 s4 -> f1 (fp32) 128x32x55x55
// f1 -> conv2 64x32x4x4 s2 -> f2 (fp32) 128x64x26x26
// f2 -> conv3 64x64x3x3 s1 -> x rows fp32 (36864 + 90 history, pad 36960)
// Convs: split-f16 MFMA (hi+lo decomposition, 3 MFMAs/product, fp32-quality —
// plain f16 flipped spikes: r6 absmax 0.74). fc1 fp32 split-K; LIF recurrence.
// ---------------------------------------------------------------------------

// Split conv weights into f16 hi/lo pairs [oc][k]; transpose w2 -> [k][j].
__global__ __launch_bounds__(256) void prep_weights_kernel(
    const float* __restrict__ cw1, const float* __restrict__ cw2,
    const float* __restrict__ cw3, const float* __restrict__ w2,
    f16* __restrict__ w1h, f16* __restrict__ w1l,
    f16* __restrict__ w2h, f16* __restrict__ w2l,
    f16* __restrict__ w3h, f16* __restrict__ w3l,
    float* __restrict__ w2t) {
  int i = blockIdx.x * 256 + threadIdx.x;   // grid covers 36864
  if (i < 6144)  { float v = cw1[i]; f16 h = (f16)v; w1h[i] = h; w1l[i] = (f16)(v - (float)h); }
  if (i < 32768) { float v = cw2[i]; f16 h = (f16)v; w2h[i] = h; w2l[i] = (f16)(v - (float)h); }
  if (i < 36864) { float v = cw3[i]; f16 h = (f16)v; w3h[i] = h; w3l[i] = (f16)(v - (float)h); }
  if (i < 32768) { int j = i >> 7, k = i & 127;  w2t[k * 256 + j] = w2[i]; }
}

// Copy w1 (128 x 36954) into padded rows (128 x 36960), zero tail.
__global__ __launch_bounds__(256) void pad_w1_kernel(
    const float* __restrict__ w1, float* __restrict__ w1p) {
  int i = blockIdx.x * 256 + threadIdx.x;   // float2 slots: 128 * 18480
  if (i < 128 * 18480) {
    int j = i / 18480, c = i - j * 18480;
    float2 v;
    if (c < 18477) v = *(const float2*)&w1[(size_t)j * 36954 + c * 2];
    else v = make_float2(0.f, 0.f);
    *(float2*)&w1p[(size_t)j * XS + c * 2] = v;
  }
}

// Implicit-im2col split-f16 MFMA conv. GEMM: C[oc][pos] = W[oc][K]*Im[K][pos].
// 16x16x32 MFMA layouts (HW-verified): A[m=lane&15][k=quad*8+j],
// B[k=quad*8+j][n=lane&15], C col=lane&15 row=quad*4+reg.
// LDS slots hold fragments in lane-linear order (b128 rd/wr, conflict-free).
// Split: v = hi + lo (f16 each); product = ah*bh + ah*bl + al*bh (3 MFMAs),
// dropped al*bl <= 2^-22 rel -> fp32-equivalent accuracy.
// 4 waves/block, each computes 32oc x 32pos (2x2 tiles, 12 MFMAs/chunk).
template<int IC, int KHW, int KW, int IH, int IW, int OW, int OHW,
         int S, int OC, int NPB, bool OUT_X>
__global__ __launch_bounds__(256) void mfma_conv_kernel(
    const float* __restrict__ in, const f16* __restrict__ wh,
    const f16* __restrict__ wl, const float* __restrict__ bias,
    float* __restrict__ out) {
  constexpr int K = IC * KHW;
  constexpr int KCH = K / 32;           // 6 / 16 / 18
  constexpr int MTILES = OC / 16;       // 2 / 4
  constexpr int NTILES = NPB / 16;      // 8 / 4
  constexpr int WOC = MTILES / 2;       // 1 / 2
  constexpr int ASLOTS = OC * 4;        // 128 / 256
  constexpr int BSLOTS = NPB * 4;       // 512 / 256
  __shared__ f16 Ah[MTILES * 512], Al[MTILES * 512];
  __shared__ f16 Bh[NTILES * 512], Bl[NTILES * 512];

  const int n = blockIdx.y;
  const int pos0 = blockIdx.x * NPB;
  const int t = threadIdx.x;
  const int w = t >> 6, lane = t & 63, quad = lane >> 4, l16 = lane & 15;
  const int woc  = (WOC == 1) ? 0 : (w & 1);
  const int wpos = (WOC == 1) ? w : (w >> 1);

  f32x4 acc[2][2] = {};
  const size_t in_n = (size_t)n * IC * IH * IW;

  for (int kt = 0; kt < KCH; ++kt) {
    __syncthreads();
    if (t < ASLOTS) {   // stage weights: 8 consecutive k for one oc
      int mt = t >> 6, kq = (t >> 4) & 3, mrem = t & 15;
      int m = mt * 16 + mrem;
      *(f16x8*)&Ah[t * 8] = *(const f16x8*)&wh[m * K + kt * 32 + kq * 8];
      *(f16x8*)&Al[t * 8] = *(const f16x8*)&wl[m * K + kt * 32 + kq * 8];
    }
    for (int s = t; s < BSLOTS; s += 256) {  // stage im2col gather + split
      int nt = s >> 6, kq = (s >> 4) & 3, prem = s & 15;
      int pos = pos0 + nt * 16 + prem;
      if (pos > OHW - 1) pos = OHW - 1;      // clamp (store masked later)
      int oh = pos / OW, ow = pos - oh * OW;
      int kb = kt * 32 + kq * 8;
      f16x8 bh, bl;
#pragma unroll
      for (int j = 0; j < 8; ++j) {
        int k = kb + j;
        int c = k / KHW, r = k - c * KHW;
        int kh = r / KW, kw = r - kh * KW;
        float v = in[in_n + ((size_t)c * IH + oh * S + kh) * IW + ow * S + kw];
        f16 h = (f16)v;
        bh[j] = h;
        bl[j] = (f16)(v - (float)h);
      }
      *(f16x8*)&Bh[s * 8] = bh;
      *(f16x8*)&Bl[s * 8] = bl;
    }
    __syncthreads();
    f16x8 ah0 = *(const f16x8*)&Ah[(woc * 2 + 0) * 512 + lane * 8];
    f16x8 ah1 = *(const f16x8*)&Ah[(woc * 2 + 1) * 512 + lane * 8];
    f16x8 al0 = *(const f16x8*)&Al[(woc * 2 + 0) * 512 + lane * 8];
    f16x8 al1 = *(const f16x8*)&Al[(woc * 2 + 1) * 512 + lane * 8];
    f16x8 bh0 = *(const f16x8*)&Bh[(wpos * 2 + 0) * 512 + lane * 8];
    f16x8 bh1 = *(const f16x8*)&Bh[(wpos * 2 + 1) * 512 + lane * 8];
    f16x8 bl0 = *(const f16x8*)&Bl[(wpos * 2 + 0) * 512 + lane * 8];
    f16x8 bl1 = *(const f16x8*)&Bl[(wpos * 2 + 1) * 512 + lane * 8];
    acc[0][0] = __builtin_amdgcn_mfma_f32_16x16x32_f16(ah0, bh0, acc[0][0], 0, 0, 0);
    acc[0][0] = __builtin_amdgcn_mfma_f32_16x16x32_f16(ah0, bl0, acc[0][0], 0, 0, 0);
    acc[0][0] = __builtin_amdgcn_mfma_f32_16x16x32_f16(al0, bh0, acc[0][0], 0, 0, 0);
    acc[1][0] = __builtin_amdgcn_mfma_f32_16x16x32_f16(ah1, bh0, acc[1][0], 0, 0, 0);
    acc[1][0] = __builtin_amdgcn_mfma_f32_16x16x32_f16(ah1, bl0, acc[1][0], 0, 0, 0);
    acc[1][0] = __builtin_amdgcn_mfma_f32_16x16x32_f16(al1, bh0, acc[1][0], 0, 0, 0);
    acc[0][1] = __builtin_amdgcn_mfma_f32_16x16x32_f16(ah0, bh1, acc[0][1], 0, 0, 0);
    acc[0][1] = __builtin_amdgcn_mfma_f32_16x16x32_f16(ah0, bl1, acc[0][1], 0, 0, 0);
    acc[0][1] = __builtin_amdgcn_mfma_f32_16x16x32_f16(al0, bh1, acc[0][1], 0, 0, 0);
    acc[1][1] = __builtin_amdgcn_mfma_f32_16x16x32_f16(ah1, bh1, acc[1][1], 0, 0, 0);
    acc[1][1] = __builtin_amdgcn_mfma_f32_16x16x32_f16(ah1, bl1, acc[1][1], 0, 0, 0);
    acc[1][1] = __builtin_amdgcn_mfma_f32_16x16x32_f16(al1, bh1, acc[1][1], 0, 0, 0);
  }
#pragma unroll
  for (int mtl = 0; mtl < 2; ++mtl)
#pragma unroll
    for (int ntl = 0; ntl < 2; ++ntl)
#pragma unroll
      for (int r = 0; r < 4; ++r) {
        int oc  = (woc * 2 + mtl) * 16 + quad * 4 + r;
        int pos = pos0 + (wpos * 2 + ntl) * 16 + l16;
        if (pos < OHW) {
          float v = acc[mtl][ntl][r] + bias[oc];
          v = v > 0.f ? v : 0.f;
          if (OUT_X)
            out[(size_t)n * XS + oc * OHW + pos] = v;
          else
            out[((size_t)n * OC + oc) * OHW + pos] = v;
        }
      }
}

// history -> x[:, 36864:36954], zero the pad to 36960
__global__ __launch_bounds__(256) void histpack_kernel(
    const float* __restrict__ h, float* __restrict__ x) {
  int i = blockIdx.x * 256 + threadIdx.x;
  if (i < 128 * 96) {
    int n = i / 96, k = i % 96;
    x[(size_t)n * XS + 36864 + k] = (k < 90) ? h[n * 90 + k] : 0.f;
  }
}

// FC1 (fp32): register-blocked split-K GEMM, 128b x 128j tile per block,
// thread owns 8x8 interleaved sub-tile. P[kt][b][j] deterministic partials.
#define FC1_KT 289
__global__ __launch_bounds__(256) void fc1_kernel(
    const float* __restrict__ x, const float* __restrict__ w1p,
    float* __restrict__ P) {
  int kt = blockIdx.x;        // 0..288
  int t  = threadIdx.x;
  int bq = t & 15, jq = t >> 4;
  __shared__ float xs[128 * 36];
  __shared__ float wsm[128 * 36];
  float acc[8][8];
#pragma unroll
  for (int bb = 0; bb < 8; ++bb)
#pragma unroll
    for (int jj = 0; jj < 8; ++jj) acc[bb][jj] = 0.f;

  int cs = t & 7;          // float4 column for staging (0..7)
  int rs = t >> 3;         // row base for staging (0..31), 4 passes
#pragma unroll 1
  for (int s = 0; s < 4; ++s) {
    int k0 = kt * 128 + s * 32;
    __syncthreads();
#pragma unroll
    for (int p = 0; p < 4; ++p) {
      int r = rs + p * 32;
      int gk = k0 + cs * 4;
      float4 xv, wv;
      if (gk < 36954) {
        xv = *(const float4*)&x[(size_t)r * XS + gk];
        wv = *(const float4*)&w1p[(size_t)r * XS + gk];
      } else {
        xv = make_float4(0.f, 0.f, 0.f, 0.f);
        wv = make_float4(0.f, 0.f, 0.f, 0.f);
      }
      *(float4*)&xs[r * 36 + cs * 4] = xv;
      *(float4*)&wsm[r * 36 + cs * 4] = wv;
    }
    __syncthreads();
#pragma unroll 1
    for (int kk = 0; kk < 32; kk += 4) {
      float4 xv[8], wv[8];
#pragma unroll
      for (int i = 0; i < 8; ++i)
        xv[i] = *(const float4*)&xs[(bq + 16 * i) * 36 + kk];
#pragma unroll
      for (int i = 0; i < 8; ++i)
        wv[i] = *(const float4*)&wsm[(jq + 16 * i) * 36 + kk];
#pragma unroll
      for (int bb = 0; bb < 8; ++bb)
#pragma unroll
        for (int jj = 0; jj < 8; ++jj) {
          acc[bb][jj] = fmaf(xv[bb].x, wv[jj].x, acc[bb][jj]);
          acc[bb][jj] = fmaf(xv[bb].y, wv[jj].y, acc[bb][jj]);
          acc[bb][jj] = fmaf(xv[bb].z, wv[jj].z, acc[bb][jj]);
          acc[bb][jj] = fmaf(xv[bb].w, wv[jj].w, acc[bb][jj]);
        }
    }
  }
  float* Pb = P + (size_t)kt * 16384;
#pragma unroll
  for (int bb = 0; bb < 8; ++bb)
#pragma unroll
    for (int jj = 0; jj < 8; ++jj)
      Pb[(bq + 16 * bb) * 128 + jq + 16 * jj] = acc[bb][jj];
}

// Reduce P over kt: h1s[b][j] = sum_kt P[kt][b][j] + b1[j].
__global__ __launch_bounds__(256) void reduce_p_kernel(
    const float* __restrict__ P, const float* __restrict__ b1,
    float* __restrict__ h1s) {
  int idx = blockIdx.x * 256 + threadIdx.x;   // 0..16383
  int j = idx & 127;
  float a0 = 0.f, a1 = 0.f, a2 = 0.f, a3 = 0.f;
  int kt = 0;
#pragma unroll 2
  for (; kt + 3 < FC1_KT; kt += 4) {
    a0 += P[(size_t)(kt + 0) * 16384 + idx];
    a1 += P[(size_t)(kt + 1) * 16384 + idx];
    a2 += P[(size_t)(kt + 2) * 16384 + idx];
    a3 += P[(size_t)(kt + 3) * 16384 + idx];
  }
  for (; kt < FC1_KT; ++kt) a0 += P[(size_t)kt * 16384 + idx];
  h1s[idx] = ((a0 + a1) + (a2 + a3)) + b1[j];
}

// Recurrence: one block per batch row; h1 precomputed; runs T=10.
__global__ __launch_bounds__(256) void recur_kernel(
    const float* __restrict__ h1s,  // [128][128]
    const float* __restrict__ w2t,  // [128][256]
    const float* __restrict__ b2,
    const float* __restrict__ w3,   // [9][256]
    const float* __restrict__ b3,
    float* __restrict__ out) {      // [128][9]
  int b = blockIdx.x;
  int t = threadIdx.x;
  __shared__ float spk1s[128];
  __shared__ float spk2s[256];
  float h1 = 0.f, mem1 = 0.f, syn1 = 0.f;
  if (t < 128) h1 = h1s[b * 128 + t];
  float mem2 = 0.f, syn2 = 0.f;
  float b2v = b2[t];
  float mem3 = 0.f, syn3 = 0.f, pot = 0.f;
  float b3v = (t < 9) ? b3[t] : 0.f;

  for (int step = 0; step < 10; ++step) {
    if (t < 128) {
      syn1 = ALPHA * syn1 + h1;
      mem1 = BETA * mem1 + syn1;
      float s = (mem1 > 1.0f) ? 1.0f : 0.0f;
      mem1 -= s;
      spk1s[t] = s;
    }
    __syncthreads();
    float h2 = b2v;
#pragma unroll 8
    for (int k = 0; k < 128; ++k)
      h2 = fmaf(spk1s[k], w2t[k * 256 + t], h2);
    syn2 = ALPHA * syn2 + h2;
    mem2 = BETA * mem2 + syn2;
    float s2 = (mem2 > 1.0f) ? 1.0f : 0.0f;
    mem2 -= s2;
    spk2s[t] = s2;
    __syncthreads();
    if (t < 9) {
      float a0 = 0.f, a1 = 0.f, a2 = 0.f, a3 = 0.f;
      const float* wr = w3 + t * 256;
      for (int k = 0; k < 256; k += 4) {
        a0 = fmaf(spk2s[k],     wr[k],     a0);
        a1 = fmaf(spk2s[k + 1], wr[k + 1], a1);
        a2 = fmaf(spk2s[k + 2], wr[k + 2], a2);
        a3 = fmaf(spk2s[k + 3], wr[k + 3], a3);
      }
      float h3 = b3v + (a0 + a1) + (a2 + a3);
      syn3 = ALPHA * syn3 + h3;
      mem3 = BETA * mem3 + syn3;
      pot += mem3;
    }
    __syncthreads();
  }
  if (t < 9) out[b * 9 + t] = pot * 0.1f;
}

extern "C" void kernel_launch(void* const* d_in, const int* in_sizes, int n_in,
                              void* d_out, int out_size, void* d_ws, size_t ws_size,
                              hipStream_t stream) {
  const float* state   = (const float*)d_in[0];
  const float* history = (const float*)d_in[1];
  const float* cw1 = (const float*)d_in[2];
  const float* cb1 = (const float*)d_in[3];
  const float* cw2 = (const float*)d_in[4];
  const float* cb2 = (const float*)d_in[5];
  const float* cw3 = (const float*)d_in[6];
  const float* cb3 = (const float*)d_in[7];
  const float* w1  = (const float*)d_in[8];
  const float* b1  = (const float*)d_in[9];
  const float* w2  = (const float*)d_in[10];
  const float* b2  = (const float*)d_in[11];
  const float* w3  = (const float*)d_in[12];
  const float* b3  = (const float*)d_in[13];
  float* out = (float*)d_out;
  char* ws = (char*)d_ws;

  // workspace (bytes), time-multiplexed:
  //  f1  fp32 [0, 49,561,600)           conv1 -> conv2
  //    xb  [0, 18,923,520)              conv3 -> fc1   (f1 dead)
  //    w1p [18,923,520, 37,847,040)     pad_w1 (after conv2) -> fc1
  //  f2  fp32 [49,561,600, 71,712,768)  conv2 -> conv3
  //    P   [49,561,600, 68,501,504)     fc1 -> reduce  (f2 dead)
  //  small weights [71,712,768, 72,212,480)
  float* f1  = (float*)(ws + 0);
  float* xb  = (float*)(ws + 0);
  float* w1p = (float*)(ws + 18923520);
  float* f2  = (float*)(ws + 49561600);
  float* P   = (float*)(ws + 49561600);
  f16* wf1h = (f16*)(ws + 71712768);   // 12,288
  f16* wf1l = (f16*)(ws + 71725056);   // 12,288
  f16* wf2h = (f16*)(ws + 71737344);   // 65,536
  f16* wf2l = (f16*)(ws + 71802880);   // 65,536
  f16* wf3h = (f16*)(ws + 71868416);   // 73,728
  f16* wf3l = (f16*)(ws + 71942144);   // 73,728
  float* w2t = (float*)(ws + 72015872);  // 131,072
  float* h1s = (float*)(ws + 72146944);  // 65,536 (end 72,212,480)

  prep_weights_kernel<<<144, 256, 0, stream>>>(cw1, cw2, cw3, w2,
                                               wf1h, wf1l, wf2h, wf2l,
                                               wf3h, wf3l, w2t);
  // conv1: IC=3,KHW=64,KW=8,IH=IW=224,OW=55,OHW=3025,S=4,OC=32,NPB=128
  mfma_conv_kernel<3, 64, 8, 224, 224, 55, 3025, 4, 32, 128, false>
      <<<dim3(24, 128), 256, 0, stream>>>(state, wf1h, wf1l, cb1, f1);
  // conv2: IC=32,KHW=16,KW=4,IH=IW=55,OW=26,OHW=676,S=2,OC=64,NPB=64
  mfma_conv_kernel<32, 16, 4, 55, 55, 26, 676, 2, 64, 64, false>
      <<<dim3(11, 128), 256, 0, stream>>>(f1, wf2h, wf2l, cb2, f2);
  pad_w1_kernel<<<9240, 256, 0, stream>>>(w1, w1p);
  // conv3: IC=64,KHW=9,KW=3,IH=IW=26,OW=24,OHW=576,S=1,OC=64,NPB=64 -> x
  mfma_conv_kernel<64, 9, 3, 26, 26, 24, 576, 1, 64, 64, true>
      <<<dim3(9, 128), 256, 0, stream>>>(f2, wf3h, wf3l, cb3, xb);
  histpack_kernel<<<48, 256, 0, stream>>>(history, xb);
  fc1_kernel<<<FC1_KT, 256, 0, stream>>>(xb, w1p, P);
  reduce_p_kernel<<<64, 256, 0, stream>>>(P, b1, h1s);
  recur_kernel<<<128, 256, 0, stream>>>(h1s, w2t, b2, w3, b3, out);
}

// Round 8
// 379.372 us; speedup vs baseline: 1.2461x; 1.1805x over previous
//
#include <hip/hip_runtime.h>

#define ALPHA 0.9f
#define BETA  0.8f
#define XS 36960   // padded row stride for x and w1p

typedef _Float16 f16;
typedef _Float16 f16x8 __attribute__((ext_vector_type(8)));
typedef float f32x4 __attribute__((ext_vector_type(4)));

// ---------------------------------------------------------------------------
// state: 128x3x224x224  conv1 32x3x8x8 s4 -> f1 (fp32) 128x32x55x55
// f1 -> conv2 64x32x4x4 s2 -> f2 (fp32) 128x64x26x26
// f2 -> conv3 64x64x3x3 s1 -> x rows fp32 (36864 + 90 history, pad 36960)
// Convs: split-f16 MFMA (hi+lo, 3 MFMAs/product, fp32-quality: r7 absmax 0.0).
// r8: vectorized im2col gather — fragment k-groups = contiguous filter-row
// pixels; conv3 K padded 576->768 (KWP=4, kw=3 zeroed) for vector loads.
// ---------------------------------------------------------------------------

// Split conv weights into f16 hi/lo pairs; conv3 padded [oc][c][kh][4]
// (kw=3 -> 0). Transpose w2 -> [k][j].
__global__ __launch_bounds__(256) void prep_weights_kernel(
    const float* __restrict__ cw1, const float* __restrict__ cw2,
    const float* __restrict__ cw3, const float* __restrict__ w2,
    f16* __restrict__ w1h, f16* __restrict__ w1l,
    f16* __restrict__ w2h, f16* __restrict__ w2l,
    f16* __restrict__ w3h, f16* __restrict__ w3l,
    float* __restrict__ w2t) {
  int i = blockIdx.x * 256 + threadIdx.x;   // grid covers 49152
  if (i < 6144)  { float v = cw1[i]; f16 h = (f16)v; w1h[i] = h; w1l[i] = (f16)(v - (float)h); }
  if (i < 32768) { float v = cw2[i]; f16 h = (f16)v; w2h[i] = h; w2l[i] = (f16)(v - (float)h); }
  if (i < 49152) {
    int oc = i / 768, r = i % 768;
    int c = r / 12, rr = r % 12, kh = rr >> 2, kw = rr & 3;
    float v = (kw < 3) ? cw3[oc * 576 + c * 9 + kh * 3 + kw] : 0.f;
    f16 h = (f16)v; w3h[i] = h; w3l[i] = (f16)(v - (float)h);
  }
  if (i < 32768) { int j = i >> 7, k = i & 127;  w2t[k * 256 + j] = w2[i]; }
}

// Copy w1 (128 x 36954) into padded rows (128 x 36960), zero tail.
__global__ __launch_bounds__(256) void pad_w1_kernel(
    const float* __restrict__ w1, float* __restrict__ w1p) {
  int i = blockIdx.x * 256 + threadIdx.x;   // float2 slots: 128 * 18480
  if (i < 128 * 18480) {
    int j = i / 18480, c = i - j * 18480;
    float2 v;
    if (c < 18477) v = *(const float2*)&w1[(size_t)j * 36954 + c * 2];
    else v = make_float2(0.f, 0.f);
    *(float2*)&w1p[(size_t)j * XS + c * 2] = v;
  }
}

// Implicit-im2col split-f16 MFMA conv. GEMM: C[oc][pos] = W[oc][K]*Im[K][pos],
// K = IC*KH*KWP (KWP-padded filter rows; kw >= KWV compile-time-zeroed).
// 16x16x32 MFMA layouts (HW-verified): A[m=lane&15][k=quad*8+j],
// B[k=quad*8+j][n=lane&15], C col=lane&15 row=quad*4+reg. LDS slots hold
// fragments lane-linear (b128 rd/wr, conflict-free). Split-f16:
// product = ah*bh + ah*bl + al*bh (3 MFMAs), fp32-equivalent.
// Gather: 8 slot k's = 2 groups of 4 contiguous input pixels -> 2 vector
// loads; pos->(oh,ow) hoisted out of the K-loop.
template<int IC, int KH, int KWP, int KWV, int S, int IH, int IW,
         int OW, int OHW, int OC, int NPB, bool OUT_X>
__global__ __launch_bounds__(256) void mfma_conv_kernel(
    const float* __restrict__ in, const f16* __restrict__ wh,
    const f16* __restrict__ wl, const float* __restrict__ bias,
    float* __restrict__ out) {
  constexpr int K = IC * KH * KWP;      // 192 / 512 / 768
  constexpr int KCH = K / 32;           // 6 / 16 / 24
  constexpr int MTILES = OC / 16;       // 2 / 4
  constexpr int NTILES = NPB / 16;      // 8 / 4
  constexpr int WOC = MTILES / 2;       // 1 / 2
  constexpr int ASLOTS = OC * 4;        // 128 / 256
  constexpr int BSLOTS = NPB * 4;       // 512 / 256
  constexpr int SITER = BSLOTS / 256;   // 2 / 1
  __shared__ f16 Ah[MTILES * 512], Al[MTILES * 512];
  __shared__ f16 Bh[NTILES * 512], Bl[NTILES * 512];

  const int n = blockIdx.y;
  const int pos0 = blockIdx.x * NPB;
  const int t = threadIdx.x;
  const int w = t >> 6, lane = t & 63, quad = lane >> 4, l16 = lane & 15;
  const int woc  = (WOC == 1) ? 0 : (w & 1);
  const int wpos = (WOC == 1) ? w : (w >> 1);
  const size_t in_n = (size_t)n * IC * IH * IW;

  // Per-slot invariants (hoisted out of K-loop)
  int ohS[SITER], owS[SITER], kq8[SITER];
#pragma unroll
  for (int si = 0; si < SITER; ++si) {
    int s = t + si * 256;
    int nt = s >> 6, prem = s & 15;
    int pos = pos0 + nt * 16 + prem;
    if (pos > OHW - 1) pos = OHW - 1;    // clamp (store masked later)
    int oh = pos / OW, ow = pos - oh * OW;
    ohS[si] = oh * S; owS[si] = ow * S;
    kq8[si] = ((s >> 4) & 3) * 8;
  }
  const int am = (t >> 6) * 16 + (t & 15);          // A slot oc
  const int ak = ((t >> 4) & 3) * 8;                // A slot k offset

  f32x4 acc[2][2] = {};

  for (int kt = 0; kt < KCH; ++kt) {
    __syncthreads();
    if (t < ASLOTS) {   // stage weights: 8 consecutive k for one oc
      *(f16x8*)&Ah[t * 8] = *(const f16x8*)&wh[am * K + kt * 32 + ak];
      *(f16x8*)&Al[t * 8] = *(const f16x8*)&wl[am * K + kt * 32 + ak];
    }
#pragma unroll
    for (int si = 0; si < SITER; ++si) {  // stage im2col gather + split
      int s = t + si * 256;
      int kb = kt * 32 + kq8[si];
      f16x8 bh, bl;
#pragma unroll
      for (int half = 0; half < 2; ++half) {
        int kk = kb + half * 4;
        int kw0 = kk & (KWP - 1);          // 0 or 4 (KWP=8); 0 (KWP=4)
        int row = kk / KWP;
        int c = row / KH, kh = row - c * KH;
        const float* p = in + in_n +
            ((size_t)c * IH + ohS[si] + kh) * IW + owS[si] + kw0;
#pragma unroll
        for (int e = 0; e < 4; ++e) {
          float v = (KWV < KWP && e >= KWV) ? 0.f : p[e];
          f16 h = (f16)v;
          bh[half * 4 + e] = h;
          bl[half * 4 + e] = (f16)(v - (float)h);
        }
      }
      *(f16x8*)&Bh[s * 8] = bh;
      *(f16x8*)&Bl[s * 8] = bl;
    }
    __syncthreads();
    f16x8 ah0 = *(const f16x8*)&Ah[(woc * 2 + 0) * 512 + lane * 8];
    f16x8 ah1 = *(const f16x8*)&Ah[(woc * 2 + 1) * 512 + lane * 8];
    f16x8 al0 = *(const f16x8*)&Al[(woc * 2 + 0) * 512 + lane * 8];
    f16x8 al1 = *(const f16x8*)&Al[(woc * 2 + 1) * 512 + lane * 8];
    f16x8 bh0 = *(const f16x8*)&Bh[(wpos * 2 + 0) * 512 + lane * 8];
    f16x8 bh1 = *(const f16x8*)&Bh[(wpos * 2 + 1) * 512 + lane * 8];
    f16x8 bl0 = *(const f16x8*)&Bl[(wpos * 2 + 0) * 512 + lane * 8];
    f16x8 bl1 = *(const f16x8*)&Bl[(wpos * 2 + 1) * 512 + lane * 8];
    acc[0][0] = __builtin_amdgcn_mfma_f32_16x16x32_f16(ah0, bh0, acc[0][0], 0, 0, 0);
    acc[0][0] = __builtin_amdgcn_mfma_f32_16x16x32_f16(ah0, bl0, acc[0][0], 0, 0, 0);
    acc[0][0] = __builtin_amdgcn_mfma_f32_16x16x32_f16(al0, bh0, acc[0][0], 0, 0, 0);
    acc[1][0] = __builtin_amdgcn_mfma_f32_16x16x32_f16(ah1, bh0, acc[1][0], 0, 0, 0);
    acc[1][0] = __builtin_amdgcn_mfma_f32_16x16x32_f16(ah1, bl0, acc[1][0], 0, 0, 0);
    acc[1][0] = __builtin_amdgcn_mfma_f32_16x16x32_f16(al1, bh0, acc[1][0], 0, 0, 0);
    acc[0][1] = __builtin_amdgcn_mfma_f32_16x16x32_f16(ah0, bh1, acc[0][1], 0, 0, 0);
    acc[0][1] = __builtin_amdgcn_mfma_f32_16x16x32_f16(ah0, bl1, acc[0][1], 0, 0, 0);
    acc[0][1] = __builtin_amdgcn_mfma_f32_16x16x32_f16(al0, bh1, acc[0][1], 0, 0, 0);
    acc[1][1] = __builtin_amdgcn_mfma_f32_16x16x32_f16(ah1, bh1, acc[1][1], 0, 0, 0);
    acc[1][1] = __builtin_amdgcn_mfma_f32_16x16x32_f16(ah1, bl1, acc[1][1], 0, 0, 0);
    acc[1][1] = __builtin_amdgcn_mfma_f32_16x16x32_f16(al1, bh1, acc[1][1], 0, 0, 0);
  }
#pragma unroll
  for (int mtl = 0; mtl < 2; ++mtl)
#pragma unroll
    for (int ntl = 0; ntl < 2; ++ntl)
#pragma unroll
      for (int r = 0; r < 4; ++r) {
        int oc  = (woc * 2 + mtl) * 16 + quad * 4 + r;
        int pos = pos0 + (wpos * 2 + ntl) * 16 + l16;
        if (pos < OHW) {
          float v = acc[mtl][ntl][r] + bias[oc];
          v = v > 0.f ? v : 0.f;
          if (OUT_X)
            out[(size_t)n * XS + oc * OHW + pos] = v;
          else
            out[((size_t)n * OC + oc) * OHW + pos] = v;
        }
      }
}

// history -> x[:, 36864:36954], zero the pad to 36960
__global__ __launch_bounds__(256) void histpack_kernel(
    const float* __restrict__ h, float* __restrict__ x) {
  int i = blockIdx.x * 256 + threadIdx.x;
  if (i < 128 * 96) {
    int n = i / 96, k = i % 96;
    x[(size_t)n * XS + 36864 + k] = (k < 90) ? h[n * 90 + k] : 0.f;
  }
}

// FC1 (fp32): register-blocked split-K GEMM, 128b x 128j tile per block,
// thread owns 8x8 interleaved sub-tile. P[kt][b][j] deterministic partials.
#define FC1_KT 289
__global__ __launch_bounds__(256) void fc1_kernel(
    const float* __restrict__ x, const float* __restrict__ w1p,
    float* __restrict__ P) {
  int kt = blockIdx.x;        // 0..288
  int t  = threadIdx.x;
  int bq = t & 15, jq = t >> 4;
  __shared__ float xs[128 * 36];
  __shared__ float wsm[128 * 36];
  float acc[8][8];
#pragma unroll
  for (int bb = 0; bb < 8; ++bb)
#pragma unroll
    for (int jj = 0; jj < 8; ++jj) acc[bb][jj] = 0.f;

  int cs = t & 7;          // float4 column for staging (0..7)
  int rs = t >> 3;         // row base for staging (0..31), 4 passes
#pragma unroll 1
  for (int s = 0; s < 4; ++s) {
    int k0 = kt * 128 + s * 32;
    __syncthreads();
#pragma unroll
    for (int p = 0; p < 4; ++p) {
      int r = rs + p * 32;
      int gk = k0 + cs * 4;
      float4 xv, wv;
      if (gk < 36954) {
        xv = *(const float4*)&x[(size_t)r * XS + gk];
        wv = *(const float4*)&w1p[(size_t)r * XS + gk];
      } else {
        xv = make_float4(0.f, 0.f, 0.f, 0.f);
        wv = make_float4(0.f, 0.f, 0.f, 0.f);
      }
      *(float4*)&xs[r * 36 + cs * 4] = xv;
      *(float4*)&wsm[r * 36 + cs * 4] = wv;
    }
    __syncthreads();
#pragma unroll 1
    for (int kk = 0; kk < 32; kk += 4) {
      float4 xv[8], wv[8];
#pragma unroll
      for (int i = 0; i < 8; ++i)
        xv[i] = *(const float4*)&xs[(bq + 16 * i) * 36 + kk];
#pragma unroll
      for (int i = 0; i < 8; ++i)
        wv[i] = *(const float4*)&wsm[(jq + 16 * i) * 36 + kk];
#pragma unroll
      for (int bb = 0; bb < 8; ++bb)
#pragma unroll
        for (int jj = 0; jj < 8; ++jj) {
          acc[bb][jj] = fmaf(xv[bb].x, wv[jj].x, acc[bb][jj]);
          acc[bb][jj] = fmaf(xv[bb].y, wv[jj].y, acc[bb][jj]);
          acc[bb][jj] = fmaf(xv[bb].z, wv[jj].z, acc[bb][jj]);
          acc[bb][jj] = fmaf(xv[bb].w, wv[jj].w, acc[bb][jj]);
        }
    }
  }
  float* Pb = P + (size_t)kt * 16384;
#pragma unroll
  for (int bb = 0; bb < 8; ++bb)
#pragma unroll
    for (int jj = 0; jj < 8; ++jj)
      Pb[(bq + 16 * bb) * 128 + jq + 16 * jj] = acc[bb][jj];
}

// Reduce P over kt: h1s[b][j] = sum_kt P[kt][b][j] + b1[j].
__global__ __launch_bounds__(256) void reduce_p_kernel(
    const float* __restrict__ P, const float* __restrict__ b1,
    float* __restrict__ h1s) {
  int idx = blockIdx.x * 256 + threadIdx.x;   // 0..16383
  int j = idx & 127;
  float a0 = 0.f, a1 = 0.f, a2 = 0.f, a3 = 0.f;
  int kt = 0;
#pragma unroll 2
  for (; kt + 3 < FC1_KT; kt += 4) {
    a0 += P[(size_t)(kt + 0) * 16384 + idx];
    a1 += P[(size_t)(kt + 1) * 16384 + idx];
    a2 += P[(size_t)(kt + 2) * 16384 + idx];
    a3 += P[(size_t)(kt + 3) * 16384 + idx];
  }
  for (; kt < FC1_KT; ++kt) a0 += P[(size_t)kt * 16384 + idx];
  h1s[idx] = ((a0 + a1) + (a2 + a3)) + b1[j];
}

// Recurrence: one block per batch row; h1 precomputed; runs T=10.
__global__ __launch_bounds__(256) void recur_kernel(
    const float* __restrict__ h1s,  // [128][128]
    const float* __restrict__ w2t,  // [128][256]
    const float* __restrict__ b2,
    const float* __restrict__ w3,   // [9][256]
    const float* __restrict__ b3,
    float* __restrict__ out) {      // [128][9]
  int b = blockIdx.x;
  int t = threadIdx.x;
  __shared__ float spk1s[128];
  __shared__ float spk2s[256];
  float h1 = 0.f, mem1 = 0.f, syn1 = 0.f;
  if (t < 128) h1 = h1s[b * 128 + t];
  float mem2 = 0.f, syn2 = 0.f;
  float b2v = b2[t];
  float mem3 = 0.f, syn3 = 0.f, pot = 0.f;
  float b3v = (t < 9) ? b3[t] : 0.f;

  for (int step = 0; step < 10; ++step) {
    if (t < 128) {
      syn1 = ALPHA * syn1 + h1;
      mem1 = BETA * mem1 + syn1;
      float s = (mem1 > 1.0f) ? 1.0f : 0.0f;
      mem1 -= s;
      spk1s[t] = s;
    }
    __syncthreads();
    float h2 = b2v;
#pragma unroll 8
    for (int k = 0; k < 128; ++k)
      h2 = fmaf(spk1s[k], w2t[k * 256 + t], h2);
    syn2 = ALPHA * syn2 + h2;
    mem2 = BETA * mem2 + syn2;
    float s2 = (mem2 > 1.0f) ? 1.0f : 0.0f;
    mem2 -= s2;
    spk2s[t] = s2;
    __syncthreads();
    if (t < 9) {
      float a0 = 0.f, a1 = 0.f, a2 = 0.f, a3 = 0.f;
      const float* wr = w3 + t * 256;
      for (int k = 0; k < 256; k += 4) {
        a0 = fmaf(spk2s[k],     wr[k],     a0);
        a1 = fmaf(spk2s[k + 1], wr[k + 1], a1);
        a2 = fmaf(spk2s[k + 2], wr[k + 2], a2);
        a3 = fmaf(spk2s[k + 3], wr[k + 3], a3);
      }
      float h3 = b3v + (a0 + a1) + (a2 + a3);
      syn3 = ALPHA * syn3 + h3;
      mem3 = BETA * mem3 + syn3;
      pot += mem3;
    }
    __syncthreads();
  }
  if (t < 9) out[b * 9 + t] = pot * 0.1f;
}

extern "C" void kernel_launch(void* const* d_in, const int* in_sizes, int n_in,
                              void* d_out, int out_size, void* d_ws, size_t ws_size,
                              hipStream_t stream) {
  const float* state   = (const float*)d_in[0];
  const float* history = (const float*)d_in[1];
  const float* cw1 = (const float*)d_in[2];
  const float* cb1 = (const float*)d_in[3];
  const float* cw2 = (const float*)d_in[4];
  const float* cb2 = (const float*)d_in[5];
  const float* cw3 = (const float*)d_in[6];
  const float* cb3 = (const float*)d_in[7];
  const float* w1  = (const float*)d_in[8];
  const float* b1  = (const float*)d_in[9];
  const float* w2  = (const float*)d_in[10];
  const float* b2  = (const float*)d_in[11];
  const float* w3  = (const float*)d_in[12];
  const float* b3  = (const float*)d_in[13];
  float* out = (float*)d_out;
  char* ws = (char*)d_ws;

  // workspace (bytes), time-multiplexed:
  //  f1  fp32 [0, 49,561,600)           conv1 -> conv2
  //    xb  [0, 18,923,520)              conv3 -> fc1   (f1 dead)
  //    w1p [18,923,520, 37,847,040)     pad_w1 (after conv2) -> fc1
  //  f2  fp32 [49,561,600, 71,712,768)  conv2 -> conv3
  //    P   [49,561,600, 68,501,504)     fc1 -> reduce  (f2 dead)
  //  small weights [71,712,768, 72,261,632)
  float* f1  = (float*)(ws + 0);
  float* xb  = (float*)(ws + 0);
  float* w1p = (float*)(ws + 18923520);
  float* f2  = (float*)(ws + 49561600);
  float* P   = (float*)(ws + 49561600);
  f16* wf1h = (f16*)(ws + 71712768);   // 12,288
  f16* wf1l = (f16*)(ws + 71725056);   // 12,288
  f16* wf2h = (f16*)(ws + 71737344);   // 65,536
  f16* wf2l = (f16*)(ws + 71802880);   // 65,536
  f16* wf3h = (f16*)(ws + 71868416);   // 98,304 (padded K=768)
  f16* wf3l = (f16*)(ws + 71966720);   // 98,304
  float* w2t = (float*)(ws + 72065024);  // 131,072
  float* h1s = (float*)(ws + 72196096);  // 65,536 (end 72,261,632)

  prep_weights_kernel<<<192, 256, 0, stream>>>(cw1, cw2, cw3, w2,
                                               wf1h, wf1l, wf2h, wf2l,
                                               wf3h, wf3l, w2t);
  // conv1: IC=3,KH=8,KWP=8,KWV=8,S=4, 224x224 -> 55x55(3025), OC=32, NPB=128
  mfma_conv_kernel<3, 8, 8, 8, 4, 224, 224, 55, 3025, 32, 128, false>
      <<<dim3(24, 128), 256, 0, stream>>>(state, wf1h, wf1l, cb1, f1);
  // conv2: IC=32,KH=4,KWP=4,KWV=4,S=2, 55x55 -> 26x26(676), OC=64, NPB=64
  mfma_conv_kernel<32, 4, 4, 4, 2, 55, 55, 26, 676, 64, 64, false>
      <<<dim3(11, 128), 256, 0, stream>>>(f1, wf2h, wf2l, cb2, f2);
  pad_w1_kernel<<<9240, 256, 0, stream>>>(w1, w1p);
  // conv3: IC=64,KH=3,KWP=4,KWV=3,S=1, 26x26 -> 24x24(576), OC=64, NPB=64 -> x
  mfma_conv_kernel<64, 3, 4, 3, 1, 26, 26, 24, 576, 64, 64, true>
      <<<dim3(9, 128), 256, 0, stream>>>(f2, wf3h, wf3l, cb3, xb);
  histpack_kernel<<<48, 256, 0, stream>>>(history, xb);
  fc1_kernel<<<FC1_KT, 256, 0, stream>>>(xb, w1p, P);
  reduce_p_kernel<<<64, 256, 0, stream>>>(P, b1, h1s);
  recur_kernel<<<128, 256, 0, stream>>>(h1s, w2t, b2, w3, b3, out);
}

// Round 9
// 346.947 us; speedup vs baseline: 1.3626x; 1.0935x over previous
//
#include <hip/hip_runtime.h>

#define ALPHA 0.9f
#define BETA  0.8f
#define XS 36960   // padded row stride for x and w1p

typedef _Float16 f16;
typedef _Float16 f16x8 __attribute__((ext_vector_type(8)));
typedef float f32x4 __attribute__((ext_vector_type(4)));

// ---------------------------------------------------------------------------
// state: 128x3x224x224  conv1 32x3x8x8 s4 -> f1 (fp32) 128x32x55x55
// f1 -> conv2 64x32x4x4 s2 -> f2 (fp32) 128x64x26x26
// f2 -> conv3 64x64x3x3 s1 -> x rows fp32 (36864 + 90 history, pad 36960)
// Convs: split-f16 MFMA (hi+lo, 3 MFMAs/product, fp32-quality: r7 absmax 0.0).
// r8: vectorized im2col gather. r9: recur holds w2 columns in VGPRs (was
// latency-bound re-reading 128KB w2t from L2 every step: 52us @ 4.5% VALU).
// ---------------------------------------------------------------------------

// Split conv weights into f16 hi/lo pairs; conv3 padded [oc][c][kh][4]
// (kw=3 -> 0). Repack w2 (256x128) -> w2q[k4][j] float4 columns.
__global__ __launch_bounds__(256) void prep_weights_kernel(
    const float* __restrict__ cw1, const float* __restrict__ cw2,
    const float* __restrict__ cw3, const float* __restrict__ w2,
    f16* __restrict__ w1h, f16* __restrict__ w1l,
    f16* __restrict__ w2h, f16* __restrict__ w2l,
    f16* __restrict__ w3h, f16* __restrict__ w3l,
    float* __restrict__ w2q) {
  int i = blockIdx.x * 256 + threadIdx.x;   // grid covers 49152
  if (i < 6144)  { float v = cw1[i]; f16 h = (f16)v; w1h[i] = h; w1l[i] = (f16)(v - (float)h); }
  if (i < 32768) { float v = cw2[i]; f16 h = (f16)v; w2h[i] = h; w2l[i] = (f16)(v - (float)h); }
  if (i < 49152) {
    int oc = i / 768, r = i % 768;
    int c = r / 12, rr = r % 12, kh = rr >> 2, kw = rr & 3;
    float v = (kw < 3) ? cw3[oc * 576 + c * 9 + kh * 3 + kw] : 0.f;
    f16 h = (f16)v; w3h[i] = h; w3l[i] = (f16)(v - (float)h);
  }
  if (i < 32768) {   // w2[j][k] -> w2q[(k4*256 + j)*4 + e]
    int j = i >> 7, k = i & 127;
    w2q[((k >> 2) * 256 + j) * 4 + (k & 3)] = w2[i];
  }
}

// Copy w1 (128 x 36954) into padded rows (128 x 36960), zero tail.
__global__ __launch_bounds__(256) void pad_w1_kernel(
    const float* __restrict__ w1, float* __restrict__ w1p) {
  int i = blockIdx.x * 256 + threadIdx.x;   // float2 slots: 128 * 18480
  if (i < 128 * 18480) {
    int j = i / 18480, c = i - j * 18480;
    float2 v;
    if (c < 18477) v = *(const float2*)&w1[(size_t)j * 36954 + c * 2];
    else v = make_float2(0.f, 0.f);
    *(float2*)&w1p[(size_t)j * XS + c * 2] = v;
  }
}

// Implicit-im2col split-f16 MFMA conv. GEMM: C[oc][pos] = W[oc][K]*Im[K][pos],
// K = IC*KH*KWP (KWP-padded filter rows; kw >= KWV compile-time-zeroed).
// 16x16x32 MFMA layouts (HW-verified): A[m=lane&15][k=quad*8+j],
// B[k=quad*8+j][n=lane&15], C col=lane&15 row=quad*4+reg. LDS slots hold
// fragments lane-linear (b128 rd/wr, conflict-free). Split-f16:
// product = ah*bh + ah*bl + al*bh (3 MFMAs), fp32-equivalent.
template<int IC, int KH, int KWP, int KWV, int S, int IH, int IW,
         int OW, int OHW, int OC, int NPB, bool OUT_X>
__global__ __launch_bounds__(256) void mfma_conv_kernel(
    const float* __restrict__ in, const f16* __restrict__ wh,
    const f16* __restrict__ wl, const float* __restrict__ bias,
    float* __restrict__ out) {
  constexpr int K = IC * KH * KWP;      // 192 / 512 / 768
  constexpr int KCH = K / 32;           // 6 / 16 / 24
  constexpr int MTILES = OC / 16;       // 2 / 4
  constexpr int NTILES = NPB / 16;      // 8 / 4
  constexpr int WOC = MTILES / 2;       // 1 / 2
  constexpr int ASLOTS = OC * 4;        // 128 / 256
  constexpr int BSLOTS = NPB * 4;       // 512 / 256
  constexpr int SITER = BSLOTS / 256;   // 2 / 1
  __shared__ f16 Ah[MTILES * 512], Al[MTILES * 512];
  __shared__ f16 Bh[NTILES * 512], Bl[NTILES * 512];

  const int n = blockIdx.y;
  const int pos0 = blockIdx.x * NPB;
  const int t = threadIdx.x;
  const int w = t >> 6, lane = t & 63, quad = lane >> 4, l16 = lane & 15;
  const int woc  = (WOC == 1) ? 0 : (w & 1);
  const int wpos = (WOC == 1) ? w : (w >> 1);
  const size_t in_n = (size_t)n * IC * IH * IW;

  // Per-slot invariants (hoisted out of K-loop)
  int ohS[SITER], owS[SITER], kq8[SITER];
#pragma unroll
  for (int si = 0; si < SITER; ++si) {
    int s = t + si * 256;
    int nt = s >> 6, prem = s & 15;
    int pos = pos0 + nt * 16 + prem;
    if (pos > OHW - 1) pos = OHW - 1;    // clamp (store masked later)
    int oh = pos / OW, ow = pos - oh * OW;
    ohS[si] = oh * S; owS[si] = ow * S;
    kq8[si] = ((s >> 4) & 3) * 8;
  }
  const int am = (t >> 6) * 16 + (t & 15);          // A slot oc
  const int ak = ((t >> 4) & 3) * 8;                // A slot k offset

  f32x4 acc[2][2] = {};

  for (int kt = 0; kt < KCH; ++kt) {
    __syncthreads();
    if (t < ASLOTS) {   // stage weights: 8 consecutive k for one oc
      *(f16x8*)&Ah[t * 8] = *(const f16x8*)&wh[am * K + kt * 32 + ak];
      *(f16x8*)&Al[t * 8] = *(const f16x8*)&wl[am * K + kt * 32 + ak];
    }
#pragma unroll
    for (int si = 0; si < SITER; ++si) {  // stage im2col gather + split
      int s = t + si * 256;
      int kb = kt * 32 + kq8[si];
      f16x8 bh, bl;
#pragma unroll
      for (int half = 0; half < 2; ++half) {
        int kk = kb + half * 4;
        int kw0 = kk & (KWP - 1);          // 0 or 4 (KWP=8); 0 (KWP=4)
        int row = kk / KWP;
        int c = row / KH, kh = row - c * KH;
        const float* p = in + in_n +
            ((size_t)c * IH + ohS[si] + kh) * IW + owS[si] + kw0;
#pragma unroll
        for (int e = 0; e < 4; ++e) {
          float v = (KWV < KWP && e >= KWV) ? 0.f : p[e];
          f16 h = (f16)v;
          bh[half * 4 + e] = h;
          bl[half * 4 + e] = (f16)(v - (float)h);
        }
      }
      *(f16x8*)&Bh[s * 8] = bh;
      *(f16x8*)&Bl[s * 8] = bl;
    }
    __syncthreads();
    f16x8 ah0 = *(const f16x8*)&Ah[(woc * 2 + 0) * 512 + lane * 8];
    f16x8 ah1 = *(const f16x8*)&Ah[(woc * 2 + 1) * 512 + lane * 8];
    f16x8 al0 = *(const f16x8*)&Al[(woc * 2 + 0) * 512 + lane * 8];
    f16x8 al1 = *(const f16x8*)&Al[(woc * 2 + 1) * 512 + lane * 8];
    f16x8 bh0 = *(const f16x8*)&Bh[(wpos * 2 + 0) * 512 + lane * 8];
    f16x8 bh1 = *(const f16x8*)&Bh[(wpos * 2 + 1) * 512 + lane * 8];
    f16x8 bl0 = *(const f16x8*)&Bl[(wpos * 2 + 0) * 512 + lane * 8];
    f16x8 bl1 = *(const f16x8*)&Bl[(wpos * 2 + 1) * 512 + lane * 8];
    acc[0][0] = __builtin_amdgcn_mfma_f32_16x16x32_f16(ah0, bh0, acc[0][0], 0, 0, 0);
    acc[0][0] = __builtin_amdgcn_mfma_f32_16x16x32_f16(ah0, bl0, acc[0][0], 0, 0, 0);
    acc[0][0] = __builtin_amdgcn_mfma_f32_16x16x32_f16(al0, bh0, acc[0][0], 0, 0, 0);
    acc[1][0] = __builtin_amdgcn_mfma_f32_16x16x32_f16(ah1, bh0, acc[1][0], 0, 0, 0);
    acc[1][0] = __builtin_amdgcn_mfma_f32_16x16x32_f16(ah1, bl0, acc[1][0], 0, 0, 0);
    acc[1][0] = __builtin_amdgcn_mfma_f32_16x16x32_f16(al1, bh0, acc[1][0], 0, 0, 0);
    acc[0][1] = __builtin_amdgcn_mfma_f32_16x16x32_f16(ah0, bh1, acc[0][1], 0, 0, 0);
    acc[0][1] = __builtin_amdgcn_mfma_f32_16x16x32_f16(ah0, bl1, acc[0][1], 0, 0, 0);
    acc[0][1] = __builtin_amdgcn_mfma_f32_16x16x32_f16(al0, bh1, acc[0][1], 0, 0, 0);
    acc[1][1] = __builtin_amdgcn_mfma_f32_16x16x32_f16(ah1, bh1, acc[1][1], 0, 0, 0);
    acc[1][1] = __builtin_amdgcn_mfma_f32_16x16x32_f16(ah1, bl1, acc[1][1], 0, 0, 0);
    acc[1][1] = __builtin_amdgcn_mfma_f32_16x16x32_f16(al1, bh1, acc[1][1], 0, 0, 0);
  }
#pragma unroll
  for (int mtl = 0; mtl < 2; ++mtl)
#pragma unroll
    for (int ntl = 0; ntl < 2; ++ntl)
#pragma unroll
      for (int r = 0; r < 4; ++r) {
        int oc  = (woc * 2 + mtl) * 16 + quad * 4 + r;
        int pos = pos0 + (wpos * 2 + ntl) * 16 + l16;
        if (pos < OHW) {
          float v = acc[mtl][ntl][r] + bias[oc];
          v = v > 0.f ? v : 0.f;
          if (OUT_X)
            out[(size_t)n * XS + oc * OHW + pos] = v;
          else
            out[((size_t)n * OC + oc) * OHW + pos] = v;
        }
      }
}

// history -> x[:, 36864:36954], zero the pad to 36960
__global__ __launch_bounds__(256) void histpack_kernel(
    const float* __restrict__ h, float* __restrict__ x) {
  int i = blockIdx.x * 256 + threadIdx.x;
  if (i < 128 * 96) {
    int n = i / 96, k = i % 96;
    x[(size_t)n * XS + 36864 + k] = (k < 90) ? h[n * 90 + k] : 0.f;
  }
}

// FC1 (fp32): register-blocked split-K GEMM, 128b x 128j tile per block,
// thread owns 8x8 interleaved sub-tile. P[kt][b][j] deterministic partials.
#define FC1_KT 289
__global__ __launch_bounds__(256) void fc1_kernel(
    const float* __restrict__ x, const float* __restrict__ w1p,
    float* __restrict__ P) {
  int kt = blockIdx.x;        // 0..288
  int t  = threadIdx.x;
  int bq = t & 15, jq = t >> 4;
  __shared__ float xs[128 * 36];
  __shared__ float wsm[128 * 36];
  float acc[8][8];
#pragma unroll
  for (int bb = 0; bb < 8; ++bb)
#pragma unroll
    for (int jj = 0; jj < 8; ++jj) acc[bb][jj] = 0.f;

  int cs = t & 7;          // float4 column for staging (0..7)
  int rs = t >> 3;         // row base for staging (0..31), 4 passes
#pragma unroll 1
  for (int s = 0; s < 4; ++s) {
    int k0 = kt * 128 + s * 32;
    __syncthreads();
#pragma unroll
    for (int p = 0; p < 4; ++p) {
      int r = rs + p * 32;
      int gk = k0 + cs * 4;
      float4 xv, wv;
      if (gk < 36954) {
        xv = *(const float4*)&x[(size_t)r * XS + gk];
        wv = *(const float4*)&w1p[(size_t)r * XS + gk];
      } else {
        xv = make_float4(0.f, 0.f, 0.f, 0.f);
        wv = make_float4(0.f, 0.f, 0.f, 0.f);
      }
      *(float4*)&xs[r * 36 + cs * 4] = xv;
      *(float4*)&wsm[r * 36 + cs * 4] = wv;
    }
    __syncthreads();
#pragma unroll 1
    for (int kk = 0; kk < 32; kk += 4) {
      float4 xv[8], wv[8];
#pragma unroll
      for (int i = 0; i < 8; ++i)
        xv[i] = *(const float4*)&xs[(bq + 16 * i) * 36 + kk];
#pragma unroll
      for (int i = 0; i < 8; ++i)
        wv[i] = *(const float4*)&wsm[(jq + 16 * i) * 36 + kk];
#pragma unroll
      for (int bb = 0; bb < 8; ++bb)
#pragma unroll
        for (int jj = 0; jj < 8; ++jj) {
          acc[bb][jj] = fmaf(xv[bb].x, wv[jj].x, acc[bb][jj]);
          acc[bb][jj] = fmaf(xv[bb].y, wv[jj].y, acc[bb][jj]);
          acc[bb][jj] = fmaf(xv[bb].z, wv[jj].z, acc[bb][jj]);
          acc[bb][jj] = fmaf(xv[bb].w, wv[jj].w, acc[bb][jj]);
        }
    }
  }
  float* Pb = P + (size_t)kt * 16384;
#pragma unroll
  for (int bb = 0; bb < 8; ++bb)
#pragma unroll
    for (int jj = 0; jj < 8; ++jj)
      Pb[(bq + 16 * bb) * 128 + jq + 16 * jj] = acc[bb][jj];
}

// Reduce P over kt: h1s[b][j] = sum_kt P[kt][b][j] + b1[j].
__global__ __launch_bounds__(256) void reduce_p_kernel(
    const float* __restrict__ P, const float* __restrict__ b1,
    float* __restrict__ h1s) {
  int idx = blockIdx.x * 256 + threadIdx.x;   // 0..16383
  int j = idx & 127;
  float a0 = 0.f, a1 = 0.f, a2 = 0.f, a3 = 0.f;
  int kt = 0;
#pragma unroll 2
  for (; kt + 3 < FC1_KT; kt += 4) {
    a0 += P[(size_t)(kt + 0) * 16384 + idx];
    a1 += P[(size_t)(kt + 1) * 16384 + idx];
    a2 += P[(size_t)(kt + 2) * 16384 + idx];
    a3 += P[(size_t)(kt + 3) * 16384 + idx];
  }
  for (; kt < FC1_KT; ++kt) a0 += P[(size_t)kt * 16384 + idx];
  h1s[idx] = ((a0 + a1) + (a2 + a3)) + b1[j];
}

// Recurrence: one block per batch row. w2 column in VGPRs (loaded once,
// 32 coalesced dwordx4); spk broadcast via LDS; w3 staged in LDS; layer3
// as 144-thread partials + 9-thread reduce. Critical path ~700 cyc/step.
__global__ __launch_bounds__(256, 1) void recur_kernel(
    const float* __restrict__ h1s,  // [128][128]
    const float4* __restrict__ w2q, // [32][256] float4 cols: w2q[k4*256+j]
    const float* __restrict__ b2,
    const float* __restrict__ w3,   // [9][256]
    const float* __restrict__ b3,
    float* __restrict__ out) {      // [128][9]
  int b = blockIdx.x;
  int t = threadIdx.x;
  __shared__ float spk1s[128];
  __shared__ float spk2s[256];
  __shared__ float w3s[9 * 256];
  __shared__ float part[9][16];
  float4 w2c[32];
#pragma unroll
  for (int k4 = 0; k4 < 32; ++k4) w2c[k4] = w2q[k4 * 256 + t];
  for (int i = t; i < 9 * 256; i += 256) w3s[i] = w3[i];
  float h1 = (t < 128) ? h1s[b * 128 + t] : 0.f;
  float mem1 = 0.f, syn1 = 0.f, mem2 = 0.f, syn2 = 0.f;
  float b2v = b2[t];
  float mem3 = 0.f, syn3 = 0.f, pot = 0.f;
  float b3v = (t < 9) ? b3[t] : 0.f;
  int j3 = t >> 4, p = t & 15;      // layer3 partial owners (t < 144)
  __syncthreads();                  // w3s ready

  for (int step = 0; step < 10; ++step) {
    if (t < 128) {
      syn1 = ALPHA * syn1 + h1;
      mem1 = BETA * mem1 + syn1;
      float s = (mem1 > 1.0f) ? 1.0f : 0.0f;
      mem1 -= s;
      spk1s[t] = s;
    }
    __syncthreads();
    float h2 = b2v;
#pragma unroll
    for (int k4 = 0; k4 < 32; ++k4) {
      float4 s = *(const float4*)&spk1s[k4 * 4];   // broadcast read
      h2 = fmaf(s.x, w2c[k4].x, h2);
      h2 = fmaf(s.y, w2c[k4].y, h2);
      h2 = fmaf(s.z, w2c[k4].z, h2);
      h2 = fmaf(s.w, w2c[k4].w, h2);
    }
    syn2 = ALPHA * syn2 + h2;
    mem2 = BETA * mem2 + syn2;
    float s2 = (mem2 > 1.0f) ? 1.0f : 0.0f;
    mem2 -= s2;
    spk2s[t] = s2;
    __syncthreads();
    if (t < 144) {
      float a = 0.f;
      const float* wr = &w3s[j3 * 256 + p * 16];
      const float* sp = &spk2s[p * 16];
#pragma unroll
      for (int e = 0; e < 16; ++e) a = fmaf(sp[e], wr[e], a);
      part[j3][p] = a;
    }
    __syncthreads();
    if (t < 9) {
      float a = b3v;
#pragma unroll
      for (int p2 = 0; p2 < 16; ++p2) a += part[t][p2];
      syn3 = ALPHA * syn3 + a;
      mem3 = BETA * mem3 + syn3;
      pot += mem3;
    }
  }
  if (t < 9) out[b * 9 + t] = pot * 0.1f;
}

extern "C" void kernel_launch(void* const* d_in, const int* in_sizes, int n_in,
                              void* d_out, int out_size, void* d_ws, size_t ws_size,
                              hipStream_t stream) {
  const float* state   = (const float*)d_in[0];
  const float* history = (const float*)d_in[1];
  const float* cw1 = (const float*)d_in[2];
  const float* cb1 = (const float*)d_in[3];
  const float* cw2 = (const float*)d_in[4];
  const float* cb2 = (const float*)d_in[5];
  const float* cw3 = (const float*)d_in[6];
  const float* cb3 = (const float*)d_in[7];
  const float* w1  = (const float*)d_in[8];
  const float* b1  = (const float*)d_in[9];
  const float* w2  = (const float*)d_in[10];
  const float* b2  = (const float*)d_in[11];
  const float* w3  = (const float*)d_in[12];
  const float* b3  = (const float*)d_in[13];
  float* out = (float*)d_out;
  char* ws = (char*)d_ws;

  // workspace (bytes), time-multiplexed:
  //  f1  fp32 [0, 49,561,600)           conv1 -> conv2
  //    xb  [0, 18,923,520)              conv3 -> fc1   (f1 dead)
  //    w1p [18,923,520, 37,847,040)     pad_w1 (after conv2) -> fc1
  //  f2  fp32 [49,561,600, 71,712,768)  conv2 -> conv3
  //    P   [49,561,600, 68,501,504)     fc1 -> reduce  (f2 dead)
  //  small weights [71,712,768, 72,261,632)
  float* f1  = (float*)(ws + 0);
  float* xb  = (float*)(ws + 0);
  float* w1p = (float*)(ws + 18923520);
  float* f2  = (float*)(ws + 49561600);
  float* P   = (float*)(ws + 49561600);
  f16* wf1h = (f16*)(ws + 71712768);   // 12,288
  f16* wf1l = (f16*)(ws + 71725056);   // 12,288
  f16* wf2h = (f16*)(ws + 71737344);   // 65,536
  f16* wf2l = (f16*)(ws + 71802880);   // 65,536
  f16* wf3h = (f16*)(ws + 71868416);   // 98,304 (padded K=768)
  f16* wf3l = (f16*)(ws + 71966720);   // 98,304
  float* w2q = (float*)(ws + 72065024);  // 131,072
  float* h1s = (float*)(ws + 72196096);  // 65,536 (end 72,261,632)

  prep_weights_kernel<<<192, 256, 0, stream>>>(cw1, cw2, cw3, w2,
                                               wf1h, wf1l, wf2h, wf2l,
                                               wf3h, wf3l, w2q);
  // conv1: IC=3,KH=8,KWP=8,KWV=8,S=4, 224x224 -> 55x55(3025), OC=32, NPB=128
  mfma_conv_kernel<3, 8, 8, 8, 4, 224, 224, 55, 3025, 32, 128, false>
      <<<dim3(24, 128), 256, 0, stream>>>(state, wf1h, wf1l, cb1, f1);
  // conv2: IC=32,KH=4,KWP=4,KWV=4,S=2, 55x55 -> 26x26(676), OC=64, NPB=64
  mfma_conv_kernel<32, 4, 4, 4, 2, 55, 55, 26, 676, 64, 64, false>
      <<<dim3(11, 128), 256, 0, stream>>>(f1, wf2h, wf2l, cb2, f2);
  pad_w1_kernel<<<9240, 256, 0, stream>>>(w1, w1p);
  // conv3: IC=64,KH=3,KWP=4,KWV=3,S=1, 26x26 -> 24x24(576), OC=64, NPB=64 -> x
  mfma_conv_kernel<64, 3, 4, 3, 1, 26, 26, 24, 576, 64, 64, true>
      <<<dim3(9, 128), 256, 0, stream>>>(f2, wf3h, wf3l, cb3, xb);
  histpack_kernel<<<48, 256, 0, stream>>>(history, xb);
  fc1_kernel<<<FC1_KT, 256, 0, stream>>>(xb, w1p, P);
  reduce_p_kernel<<<64, 256, 0, stream>>>(P, b1, h1s);
  recur_kernel<<<128, 256, 0, stream>>>(h1s, (const float4*)w2q, b2, w3, b3, out);
}